// Round 1
// baseline (299.430 us; speedup 1.0000x reference)
//
#include <hip/hip_runtime.h>
#include <hip/hip_bf16.h>

#define BB 32
#define SS 64
#define DD 256
#define HH 8
#define HDIM 32
#define NSS 65
#define LN_EPS 1e-5f

// ---------------- ws layout (float offsets) ----------------
#define OFF_DESC   0u            // B*S*D   = 524288
#define OFF_U      524288u       // 524288
#define OFF_V      1048576u      // 524288
#define OFF_VBUF   1572864u      // B*NS*D  = 532480
#define OFF_NA     2105344u      // B*NS*NS = 135200
#define OFF_SE     2240544u      // B*H*NS*NS = 1081600
#define OFF_SQ     3322144u      // B*H*NS  = 16640
#define OFF_SK     3338784u      // 16640
#define OFF_CTX    3355424u      // 532480
#define OFF_WGT    3887904u      // 65536
#define OFF_WE1AT  3953440u      // 65536
#define OFF_WE1BT  4018976u      // 65536
#define OFF_WVT    4084512u      // 65536
#define OFF_WOT    4150048u      // 65536
#define OFF_WQF    4215584u      // 2048
#define OFF_WKF    4217632u      // 2048
#define OFF_MF     4219680u      // 2048
#define OFF_CVEC   4221728u      // 32  (cq[0..7], ck[8..15], ce[16..23])
#define OFF_RND    4221760u      // 2048 (1/||desc row||)
#define OFF_RNV    4223808u      // 2048 (1/||var row||)
// total 4225856 floats = 16.9 MB

// WT[k*D+o] = Wsrc[o*ld + col0 + k]
__global__ void transposeD(const float* __restrict__ Wsrc, float* __restrict__ WT,
                           int ld, int col0) {
    int k = blockIdx.x;
    int o = threadIdx.x;
    WT[k * DD + o] = Wsrc[o * ld + col0 + k];
}

// fold attention projections: wqf/wkf/Mf [H][D], cvec consts
__global__ void fold_attn(const float* __restrict__ Wq, const float* __restrict__ bq,
                          const float* __restrict__ Wk, const float* __restrict__ bk,
                          const float* __restrict__ We2, const float* __restrict__ be2,
                          const float* __restrict__ Wa,
                          float* __restrict__ wqf, float* __restrict__ wkf,
                          float* __restrict__ Mf, float* __restrict__ cvec) {
    int h = blockIdx.x;      // 0..7
    int in = threadIdx.x;    // 0..255
    float aq = 0.f, ak = 0.f, ae = 0.f;
    #pragma unroll
    for (int d = 0; d < HDIM; ++d) {
        aq = fmaf(Wq[(h * HDIM + d) * DD + in], Wa[d], aq);
        ak = fmaf(Wk[(h * HDIM + d) * DD + in], Wa[HDIM + d], ak);
        ae = fmaf(We2[(h * HDIM + d) * DD + in], Wa[2 * HDIM + d], ae);
    }
    wqf[h * DD + in] = aq;
    wkf[h * DD + in] = ak;
    Mf[h * DD + in] = ae;
    if (in == 0) {
        float cq = 0.f, ck = 0.f, ce = 0.f;
        for (int d = 0; d < HDIM; ++d) {
            cq = fmaf(bq[h * HDIM + d], Wa[d], cq);
            ck = fmaf(bk[h * HDIM + d], Wa[HDIM + d], ck);
            ce = fmaf(be2[h * HDIM + d], Wa[2 * HDIM + d], ce);
        }
        cvec[h] = cq; cvec[8 + h] = ck; cvec[16 + h] = ce;
    }
}

// out[r*D+o] = (bias? bias[o]:0) + sum_k in[r*D+k] * WT[k*D+o]
__global__ void gemm256(const float* __restrict__ in, const float* __restrict__ WT,
                        const float* __restrict__ bias, float* __restrict__ out,
                        int addBias) {
    int r = blockIdx.x;
    int o = threadIdx.x;
    __shared__ float x[DD];
    x[o] = in[r * DD + o];
    __syncthreads();
    float acc = addBias ? bias[o] : 0.f;
    #pragma unroll 8
    for (int k = 0; k < DD; ++k)
        acc = fmaf(x[k], WT[k * DD + o], acc);
    out[r * DD + o] = acc;
}

// reciprocal row norms for desc (rows 0..B*S-1) and var=nve[:,1:,:] (rows B*S..2*B*S-1)
__global__ void rownorms(const float* __restrict__ desc, const float* __restrict__ nve,
                         float* __restrict__ rnd, float* __restrict__ rnv) {
    int row = blockIdx.x;
    int lane = threadIdx.x;   // 0..63
    const float* src;
    float* dst;
    if (row < BB * SS) { src = desc + (size_t)row * DD; dst = rnd + row; }
    else {
        int r = row - BB * SS;
        int b = r / SS, s = r % SS;
        src = nve + (size_t)(b * NSS + s + 1) * DD;
        dst = rnv + r;
    }
    float ssum = 0.f;
    for (int k = lane; k < DD; k += 64) { float v = src[k]; ssum = fmaf(v, v, ssum); }
    #pragma unroll
    for (int off = 32; off; off >>= 1) ssum += __shfl_xor(ssum, off);
    if (lane == 0) *dst = 1.f / sqrtf(ssum);
}

// na[b][*][*]: adjacency softmax + borders
__global__ void adjacency_kernel(const float* __restrict__ desc, const float* __restrict__ nve,
                                 const float* __restrict__ rnd, const float* __restrict__ rnv,
                                 const float* __restrict__ tb, float* __restrict__ na) {
    int b = blockIdx.x / SS, i = blockIdx.x % SS;
    int j = threadIdx.x;     // 0..63
    __shared__ float di[DD], vi[DD];
    for (int k = j; k < DD; k += 64) {
        di[k] = desc[(size_t)(b * SS + i) * DD + k];
        vi[k] = nve[(size_t)(b * NSS + i + 1) * DD + k];
    }
    __syncthreads();
    const float* dj = desc + (size_t)(b * SS + j) * DD;
    const float* vj = nve + (size_t)(b * NSS + j + 1) * DD;
    float gd = 0.f, sv = 0.f;
    #pragma unroll 4
    for (int k = 0; k < DD; ++k) {
        gd = fmaf(di[k], dj[k], gd);
        sv = fmaf(vi[k], vj[k], sv);
    }
    float gsim = gd * rnd[b * SS + i] * rnd[b * SS + j];
    float ssim = sv * rnv[b * SS + i] * rnv[b * SS + j];
    // forward of straight-through binary: sigmoid(x)>0.5 <=> x>0 ; diag zeroed
    float P = ((gsim + tb[0] > 0.f) && (i != j)) ? ssim : 0.f;
    float m = P;
    #pragma unroll
    for (int off = 32; off; off >>= 1) m = fmaxf(m, __shfl_xor(m, off));
    float e = __expf(P - m);
    float s = e;
    #pragma unroll
    for (int off = 32; off; off >>= 1) s += __shfl_xor(s, off);
    na[(size_t)(b * NSS + i + 1) * NSS + (j + 1)] = e / s;
    if (j == 0) na[(size_t)(b * NSS + i + 1) * NSS] = 0.f;
    if (i == 0) {
        na[(size_t)(b * NSS) * NSS + (j + 1)] = 1.f;
        if (j == 0) na[(size_t)(b * NSS) * NSS] = 0.f;
    }
}

// sq/sk [B][H][NS]
__global__ void sqsk_kernel(const float* __restrict__ nve, const float* __restrict__ wqf,
                            const float* __restrict__ wkf, const float* __restrict__ cvec,
                            float* __restrict__ sq, float* __restrict__ sk) {
    int r = blockIdx.x;      // b*NS+i
    int lane = threadIdx.x;  // 0..63
    __shared__ float x[DD];
    for (int k = lane; k < DD; k += 64) x[k] = nve[(size_t)r * DD + k];
    __syncthreads();
    if (lane < 16) {
        int h = lane & 7;
        const float* w = (lane < 8) ? (wqf + h * DD) : (wkf + h * DD);
        float acc = 0.f;
        #pragma unroll 8
        for (int k = 0; k < DD; ++k) acc = fmaf(x[k], w[k], acc);
        int b = r / NSS, i = r % NSS;
        if (lane < 8) sq[(size_t)(b * HH + h) * NSS + i] = acc + cvec[h];
        else          sk[(size_t)(b * HH + h) * NSS + i] = acc + cvec[8 + h];
    }
}

// se[b][h][i][j] = na * (relu(LN(U_i + V_j + be1)) . Mf[h] + ce[h])
__global__ void se_kernel(const float* __restrict__ U, const float* __restrict__ V,
                          const float* __restrict__ be1, const float* __restrict__ lng,
                          const float* __restrict__ lnb, const float* __restrict__ Mf,
                          const float* __restrict__ cvec, const float* __restrict__ na,
                          float* __restrict__ se) {
    int idx = blockIdx.x;            // b*NS*NS + i*NS + j
    int b = idx / (NSS * NSS);
    int ij = idx % (NSS * NSS);
    int i = ij / NSS, j = ij % NSS;
    int lane = threadIdx.x;          // 0..63
    int iu = (i > 0) ? (i - 1) : ((j > 0) ? (j - 1) : -1);
    int iv = (j > 0) ? (j - 1) : ((i > 0) ? (i - 1) : -1);
    const float* Urow = (iu >= 0) ? (U + (size_t)(b * SS + iu) * DD) : nullptr;
    const float* Vrow = (iu >= 0) ? (V + (size_t)(b * SS + iv) * DD) : nullptr;
    float x[4];
    float ssum = 0.f;
    #pragma unroll
    for (int p = 0; p < 4; ++p) {
        int d = lane + 64 * p;
        float hv = be1[d];
        if (Urow) hv += Urow[d] + Vrow[d];
        x[p] = hv;
        ssum += hv;
    }
    #pragma unroll
    for (int off = 32; off; off >>= 1) ssum += __shfl_xor(ssum, off);
    float mu = ssum * (1.f / DD);
    float vs = 0.f;
    #pragma unroll
    for (int p = 0; p < 4; ++p) { float t = x[p] - mu; vs = fmaf(t, t, vs); }
    #pragma unroll
    for (int off = 32; off; off >>= 1) vs += __shfl_xor(vs, off);
    float rstd = rsqrtf(vs * (1.f / DD) + LN_EPS);
    float part[HH];
    #pragma unroll
    for (int h = 0; h < HH; ++h) part[h] = 0.f;
    #pragma unroll
    for (int p = 0; p < 4; ++p) {
        int d = lane + 64 * p;
        float xn = fmaf((x[p] - mu) * rstd, lng[d], lnb[d]);
        float r = fmaxf(xn, 0.f);
        #pragma unroll
        for (int h = 0; h < HH; ++h) part[h] = fmaf(r, Mf[h * DD + d], part[h]);
    }
    #pragma unroll
    for (int h = 0; h < HH; ++h) {
        #pragma unroll
        for (int off = 32; off; off >>= 1) part[h] += __shfl_xor(part[h], off);
    }
    if (lane == 0) {
        float nav = na[(size_t)(b * NSS + i) * NSS + j];
        #pragma unroll
        for (int h = 0; h < HH; ++h)
            se[((size_t)(b * HH + h) * NSS + i) * NSS + j] = nav * (part[h] + cvec[16 + h]);
    }
}

// per (b,h,i): scores -> softmax -> aw + ctx
__global__ void attn_kernel(const float* __restrict__ sq, const float* __restrict__ sk,
                            const float* __restrict__ se, const float* __restrict__ na,
                            const float* __restrict__ ba, const float* __restrict__ vbuf,
                            float* __restrict__ aw_out, float* __restrict__ ctx) {
    int idx = blockIdx.x;            // (b*H+h)*NS + i
    int bh = idx / NSS, i = idx % NSS;
    int b = bh / HH, h = bh % HH;
    int lane = threadIdx.x;          // 0..63
    __shared__ float awL[NSS];
    float sqv = sq[(size_t)bh * NSS + i];
    float bav = ba[0];
    float s0;
    {
        int j = lane;
        float sc = sqv + sk[(size_t)bh * NSS + j] + se[((size_t)bh * NSS + i) * NSS + j] + bav;
        if (na[(size_t)(b * NSS + i) * NSS + j] == 0.f) sc += -1e9f;
        s0 = sc;
    }
    float s1 = -3.4e38f;
    if (lane == 0) {
        int j = 64;
        float sc = sqv + sk[(size_t)bh * NSS + j] + se[((size_t)bh * NSS + i) * NSS + j] + bav;
        if (na[(size_t)(b * NSS + i) * NSS + j] == 0.f) sc += -1e9f;
        s1 = sc;
    }
    float m = fmaxf(s0, s1);
    #pragma unroll
    for (int off = 32; off; off >>= 1) m = fmaxf(m, __shfl_xor(m, off));
    float e0 = __expf(s0 - m);
    float e1 = (lane == 0) ? __expf(s1 - m) : 0.f;
    float tot = e0 + e1;
    #pragma unroll
    for (int off = 32; off; off >>= 1) tot += __shfl_xor(tot, off);
    float inv = 1.f / tot;
    float a0 = e0 * inv;
    float* awrow = aw_out + ((size_t)bh * NSS + i) * NSS;
    awL[lane] = a0;
    awrow[lane] = a0;
    if (lane == 0) { awL[64] = e1 * inv; awrow[64] = e1 * inv; }
    __syncthreads();
    if (lane < HDIM) {
        int d = lane;
        float acc = 0.f;
        #pragma unroll 5
        for (int j = 0; j < NSS; ++j)
            acc = fmaf(awL[j], vbuf[(size_t)(b * NSS + j) * DD + h * HDIM + d], acc);
        ctx[(size_t)(b * NSS + i) * DD + h * HDIM + d] = acc;
    }
}

extern "C" void kernel_launch(void* const* d_in, const int* in_sizes, int n_in,
                              void* d_out, int out_size, void* d_ws, size_t ws_size,
                              hipStream_t stream) {
    const float* desc_emb = (const float*)d_in[0];
    const float* nve      = (const float*)d_in[1];
    const float* Wg  = (const float*)d_in[2];
    const float* bg  = (const float*)d_in[3];
    const float* Wq  = (const float*)d_in[4];
    const float* bq  = (const float*)d_in[5];
    const float* Wk  = (const float*)d_in[6];
    const float* bk  = (const float*)d_in[7];
    const float* Wv  = (const float*)d_in[8];
    const float* bv  = (const float*)d_in[9];
    const float* We1 = (const float*)d_in[10];
    const float* be1 = (const float*)d_in[11];
    const float* lng = (const float*)d_in[12];
    const float* lnb = (const float*)d_in[13];
    const float* We2 = (const float*)d_in[14];
    const float* be2 = (const float*)d_in[15];
    const float* Wa  = (const float*)d_in[16];
    const float* ba  = (const float*)d_in[17];
    const float* Wo  = (const float*)d_in[18];
    const float* bo  = (const float*)d_in[19];
    const float* tb  = (const float*)d_in[20];

    float* ws   = (float*)d_ws;
    float* desc = ws + OFF_DESC;
    float* U    = ws + OFF_U;
    float* V    = ws + OFF_V;
    float* vbuf = ws + OFF_VBUF;
    float* na   = ws + OFF_NA;
    float* se   = ws + OFF_SE;
    float* sq   = ws + OFF_SQ;
    float* sk   = ws + OFF_SK;
    float* ctx  = ws + OFF_CTX;
    float* WgT   = ws + OFF_WGT;
    float* We1aT = ws + OFF_WE1AT;
    float* We1bT = ws + OFF_WE1BT;
    float* WvT   = ws + OFF_WVT;
    float* WoT   = ws + OFF_WOT;
    float* wqf  = ws + OFF_WQF;
    float* wkf  = ws + OFF_WKF;
    float* Mf   = ws + OFF_MF;
    float* cvec = ws + OFF_CVEC;
    float* rnd  = ws + OFF_RND;
    float* rnv  = ws + OFF_RNV;

    float* out = (float*)d_out;                  // [B][NS][D]
    float* aw  = out + (size_t)BB * NSS * DD;    // [B][H][NS][NS]

    transposeD<<<DD, DD, 0, stream>>>(Wg, WgT, DD, 0);
    transposeD<<<DD, DD, 0, stream>>>(We1, We1aT, 2 * DD, 0);
    transposeD<<<DD, DD, 0, stream>>>(We1, We1bT, 2 * DD, DD);
    transposeD<<<DD, DD, 0, stream>>>(Wv, WvT, DD, 0);
    transposeD<<<DD, DD, 0, stream>>>(Wo, WoT, DD, 0);
    fold_attn<<<HH, DD, 0, stream>>>(Wq, bq, Wk, bk, We2, be2, Wa, wqf, wkf, Mf, cvec);

    gemm256<<<BB * SS, DD, 0, stream>>>(desc_emb, WgT, bg, desc, 1);
    rownorms<<<2 * BB * SS, 64, 0, stream>>>(desc, nve, rnd, rnv);
    gemm256<<<BB * SS, DD, 0, stream>>>(desc, We1aT, bg, U, 0);
    gemm256<<<BB * SS, DD, 0, stream>>>(desc, We1bT, bg, V, 0);
    gemm256<<<BB * NSS, DD, 0, stream>>>(nve, WvT, bv, vbuf, 1);

    adjacency_kernel<<<BB * SS, 64, 0, stream>>>(desc, nve, rnd, rnv, tb, na);
    sqsk_kernel<<<BB * NSS, 64, 0, stream>>>(nve, wqf, wkf, cvec, sq, sk);
    se_kernel<<<BB * NSS * NSS, 64, 0, stream>>>(U, V, be1, lng, lnb, Mf, cvec, na, se);
    attn_kernel<<<BB * HH * NSS, 64, 0, stream>>>(sq, sk, se, na, ba, vbuf, aw, ctx);
    gemm256<<<BB * NSS, DD, 0, stream>>>(ctx, WoT, bo, out, 1);
}

// Round 2
// 237.000 us; speedup vs baseline: 1.2634x; 1.2634x over previous
//
#include <hip/hip_runtime.h>
#include <hip/hip_bf16.h>

#define BB 32
#define SS 64
#define DD 256
#define HH 8
#define HDIM 32
#define NSS 65
#define LN_EPS 1e-5f

// ---------------- ws layout (float offsets) ----------------
#define OFF_DESC   0u            // B*S*D   = 524288
#define OFF_U      524288u       // 524288  (be1 folded in)
#define OFF_V      1048576u      // 524288
#define OFF_VBUF   1572864u      // B*NS*D  = 532480
#define OFF_NA     2105344u      // B*NS*NS = 135200
#define OFF_SE     2240544u      // B*H*NS*NS = 1081600
#define OFF_SQ     3322144u      // B*H*NS  = 16640
#define OFF_SK     3338784u      // 16640
#define OFF_CTX    3355424u      // 532480  (PK overlaid at front: 4096 floats,
                                 //          read only by se kernels which run
                                 //          BEFORE attn writes ctx)
#define OFF_WGT    3887904u      // 65536
#define OFF_WE1AT  3953440u      // 65536
#define OFF_WE1BT  4018976u      // 65536
#define OFF_WVT    4084512u      // 65536
#define OFF_WOT    4150048u      // 65536
#define OFF_WQF    4215584u      // 2048
#define OFF_WKF    4217632u      // 2048
#define OFF_MF     4219680u      // 2048
#define OFF_CVEC   4221728u      // 32
#define OFF_RND    4221760u      // 2048
#define OFF_RNV    4223808u      // 2048
// total 4225856 floats = 16.9 MB (same footprint as round 0)

// ---- 64x64-tile transpose: dst[k*DD+o] = src[o*ld + col0 + k] ----
__global__ __launch_bounds__(256) void transT(const float* __restrict__ src,
                                              float* __restrict__ dst,
                                              int ld, int col0) {
    __shared__ float t[64][65];
    int to = blockIdx.x & 3, tk = blockIdx.x >> 2;
    int tx = threadIdx.x & 63, ty = threadIdx.x >> 6;
    #pragma unroll
    for (int r = ty; r < 64; r += 4)
        t[r][tx] = src[(size_t)(to * 64 + r) * ld + col0 + tk * 64 + tx];
    __syncthreads();
    #pragma unroll
    for (int r = ty; r < 64; r += 4)
        dst[(size_t)(tk * 64 + r) * DD + to * 64 + tx] = t[tx][r];
}

// fold attention projections: wqf/wkf/Mf [H][D], cvec consts
__global__ void fold_attn(const float* __restrict__ Wq, const float* __restrict__ bq,
                          const float* __restrict__ Wk, const float* __restrict__ bk,
                          const float* __restrict__ We2, const float* __restrict__ be2,
                          const float* __restrict__ Wa,
                          float* __restrict__ wqf, float* __restrict__ wkf,
                          float* __restrict__ Mf, float* __restrict__ cvec) {
    int h = blockIdx.x;
    int in = threadIdx.x;
    float aq = 0.f, ak = 0.f, ae = 0.f;
    #pragma unroll
    for (int d = 0; d < HDIM; ++d) {
        aq = fmaf(Wq[(h * HDIM + d) * DD + in], Wa[d], aq);
        ak = fmaf(Wk[(h * HDIM + d) * DD + in], Wa[HDIM + d], ak);
        ae = fmaf(We2[(h * HDIM + d) * DD + in], Wa[2 * HDIM + d], ae);
    }
    wqf[h * DD + in] = aq;
    wkf[h * DD + in] = ak;
    Mf[h * DD + in] = ae;
    if (in == 0) {
        float cq = 0.f, ck = 0.f, ce = 0.f;
        for (int d = 0; d < HDIM; ++d) {
            cq = fmaf(bq[h * HDIM + d], Wa[d], cq);
            ck = fmaf(bk[h * HDIM + d], Wa[HDIM + d], ck);
            ce = fmaf(be2[h * HDIM + d], Wa[2 * HDIM + d], ce);
        }
        cvec[h] = cq; cvec[8 + h] = ck; cvec[16 + h] = ce;
    }
}

// PK[d][16] = {lng[d], lnb[d], Mf[0..7][d], 0...}
__global__ void build_pk(const float* __restrict__ lng, const float* __restrict__ lnb,
                         const float* __restrict__ Mf, float* __restrict__ PK) {
    int d = threadIdx.x;
    PK[d * 16 + 0] = lng[d];
    PK[d * 16 + 1] = lnb[d];
    #pragma unroll
    for (int h = 0; h < HH; ++h) PK[d * 16 + 2 + h] = Mf[h * DD + d];
    #pragma unroll
    for (int c = 10; c < 16; ++c) PK[d * 16 + c] = 0.f;
}

// 8-row-tiled GEMM: out[r][o] = bias[o] + sum_k in[r][k]*WT[k][o]
#define GR 8
__global__ __launch_bounds__(256) void gemmR(const float* __restrict__ in,
                                             const float* __restrict__ WT,
                                             const float* __restrict__ bias,
                                             float* __restrict__ out, int addBias) {
    int r0 = blockIdx.x * GR;
    int o = threadIdx.x;
    const float* __restrict__ x = in + (size_t)r0 * DD;   // uniform -> s_load
    float acc[GR];
    #pragma unroll
    for (int r = 0; r < GR; ++r) acc[r] = 0.f;
    #pragma unroll 4
    for (int k = 0; k < DD; ++k) {
        float w = WT[(size_t)k * DD + o];
        #pragma unroll
        for (int r = 0; r < GR; ++r)
            acc[r] = fmaf(x[r * DD + k], w, acc[r]);
    }
    float bb = addBias ? bias[o] : 0.f;
    #pragma unroll
    for (int r = 0; r < GR; ++r)
        out[(size_t)(r0 + r) * DD + o] = acc[r] + bb;
}

// reciprocal row norms for desc and var rows
__global__ void rownorms(const float* __restrict__ desc, const float* __restrict__ nve,
                         float* __restrict__ rnd, float* __restrict__ rnv) {
    int row = blockIdx.x;
    int lane = threadIdx.x;
    const float* src;
    float* dst;
    if (row < BB * SS) { src = desc + (size_t)row * DD; dst = rnd + row; }
    else {
        int r = row - BB * SS;
        int b = r / SS, s = r % SS;
        src = nve + (size_t)(b * NSS + s + 1) * DD;
        dst = rnv + r;
    }
    float ssum = 0.f;
    for (int k = lane; k < DD; k += 64) { float v = src[k]; ssum = fmaf(v, v, ssum); }
    #pragma unroll
    for (int off = 32; off; off >>= 1) ssum += __shfl_xor(ssum, off);
    if (lane == 0) *dst = 1.f / sqrtf(ssum);
}

// adjacency: two-phase LDS gram (desc -> flag, var -> ssim+softmax)
__global__ __launch_bounds__(256) void adj2_kernel(
    const float* __restrict__ desc, const float* __restrict__ nve,
    const float* __restrict__ rnd, const float* __restrict__ rnv,
    const float* __restrict__ tb, float* __restrict__ na) {
    __shared__ float4 Mt[4096];
    int b = blockIdx.x >> 4;
    int itile = blockIdx.x & 15;
    int tid = threadIdx.x, lane = tid & 63;
    int i = __builtin_amdgcn_readfirstlane(itile * 4 + (tid >> 6)); // 0..63
    const int vbase = lane * 64, lx = lane & 31;

    // phase A: desc gram row i  -> flag
    const float4* Dg = (const float4*)(desc + (size_t)b * SS * DD);
    for (int g = tid; g < 4096; g += 256) {
        int j = g >> 6, f = g & 63;
        Mt[j * 64 + (f ^ (j & 31))] = Dg[g];
    }
    __syncthreads();
    const float* drow = desc + ((size_t)b * SS + i) * DD;   // uniform
    float dot = 0.f;
    #pragma unroll 8
    for (int f = 0; f < 64; ++f) {
        float4 v = Mt[vbase + (f ^ lx)];
        float4 u = *(const float4*)(drow + 4 * f);
        dot = fmaf(v.x, u.x, dot); dot = fmaf(v.y, u.y, dot);
        dot = fmaf(v.z, u.z, dot); dot = fmaf(v.w, u.w, dot);
    }
    float gsim = dot * rnd[b * SS + i] * rnd[b * SS + lane];
    bool flag = (gsim + tb[0] > 0.f) && (i != lane);
    __syncthreads();

    // phase B: var gram row i -> ssim, softmax over lanes
    const float4* Vg = (const float4*)(nve + ((size_t)b * NSS + 1) * DD);
    for (int g = tid; g < 4096; g += 256) {
        int j = g >> 6, f = g & 63;
        Mt[j * 64 + (f ^ (j & 31))] = Vg[g];
    }
    __syncthreads();
    const float* vrow = nve + ((size_t)b * NSS + 1 + i) * DD;  // uniform
    float dv = 0.f;
    #pragma unroll 8
    for (int f = 0; f < 64; ++f) {
        float4 v = Mt[vbase + (f ^ lx)];
        float4 u = *(const float4*)(vrow + 4 * f);
        dv = fmaf(v.x, u.x, dv); dv = fmaf(v.y, u.y, dv);
        dv = fmaf(v.z, u.z, dv); dv = fmaf(v.w, u.w, dv);
    }
    float ssim = dv * rnv[b * SS + i] * rnv[b * SS + lane];
    float P = flag ? ssim : 0.f;
    float m = P;
    #pragma unroll
    for (int off = 32; off; off >>= 1) m = fmaxf(m, __shfl_xor(m, off));
    float e = __expf(P - m);
    float s = e;
    #pragma unroll
    for (int off = 32; off; off >>= 1) s += __shfl_xor(s, off);
    na[((size_t)b * NSS + i + 1) * NSS + lane + 1] = e / s;
    if (lane == 0) na[((size_t)b * NSS + i + 1) * NSS] = 0.f;
    if (i == 0) {
        na[(size_t)b * NSS * NSS + lane + 1] = 1.f;
        if (lane == 0) na[(size_t)b * NSS * NSS] = 0.f;
    }
}

// sq/sk [B][H][NS]
__global__ void sqsk_kernel(const float* __restrict__ nve, const float* __restrict__ wqf,
                            const float* __restrict__ wkf, const float* __restrict__ cvec,
                            float* __restrict__ sq, float* __restrict__ sk) {
    int r = blockIdx.x;
    int lane = threadIdx.x;
    __shared__ float x[DD];
    for (int k = lane; k < DD; k += 64) x[k] = nve[(size_t)r * DD + k];
    __syncthreads();
    if (lane < 16) {
        int h = lane & 7;
        const float* w = (lane < 8) ? (wqf + h * DD) : (wkf + h * DD);
        float acc = 0.f;
        #pragma unroll 8
        for (int k = 0; k < DD; ++k) acc = fmaf(x[k], w[k], acc);
        int b = r / NSS, i = r % NSS;
        if (lane < 8) sq[(size_t)(b * HH + h) * NSS + i] = acc + cvec[h];
        else          sk[(size_t)(b * HH + h) * NSS + i] = acc + cvec[8 + h];
    }
}

// se interior: rows i=1..64, cols j=1..64. lane-local LN + head dots (no shuffles)
__global__ __launch_bounds__(256) void se2_kernel(
    const float* __restrict__ U, const float* __restrict__ V,
    const float* __restrict__ PK, const float* __restrict__ cvec,
    const float* __restrict__ na, float* __restrict__ se) {
    __shared__ float4 Vt[4096];                 // 64 KB, XOR-swizzled
    int b = blockIdx.x >> 4;
    int itile = blockIdx.x & 15;
    int tid = threadIdx.x, lane = tid & 63;
    const float4* Vg = (const float4*)(V + (size_t)b * SS * DD);
    for (int g = tid; g < 4096; g += 256) {
        int j = g >> 6, f = g & 63;
        Vt[j * 64 + (f ^ (j & 31))] = Vg[g];
    }
    __syncthreads();
    int wi = __builtin_amdgcn_readfirstlane(itile * 4 + (tid >> 6)); // 0..63
    const float* urow = U + ((size_t)b * SS + wi) * DD;   // uniform -> s_load
    const int vbase = lane * 64, lx = lane & 31;

    // pass 1: per-lane LN stats of h = U'[wi] + V[lane]
    float ss = 0.f, sqr = 0.f;
    #pragma unroll 8
    for (int f = 0; f < 64; ++f) {
        float4 v = Vt[vbase + (f ^ lx)];
        float4 u = *(const float4*)(urow + 4 * f);
        float t0 = v.x + u.x, t1 = v.y + u.y, t2 = v.z + u.z, t3 = v.w + u.w;
        ss += (t0 + t1) + (t2 + t3);
        sqr = fmaf(t0, t0, sqr); sqr = fmaf(t1, t1, sqr);
        sqr = fmaf(t2, t2, sqr); sqr = fmaf(t3, t3, sqr);
    }
    float mu = ss * (1.f / DD);
    float var = fmaf(-mu, mu, sqr * (1.f / DD));
    float rstd = rsqrtf(var + LN_EPS);

    // pass 2: relu(LN(h)) dot Mf[h], PK streamed via scalar pipe
    float part[HH];
    #pragma unroll
    for (int h = 0; h < HH; ++h) part[h] = 0.f;
    #pragma unroll 4
    for (int f = 0; f < 64; ++f) {
        float4 v = Vt[vbase + (f ^ lx)];
        float4 u = *(const float4*)(urow + 4 * f);
        const float* pk = PK + f * 64;                    // uniform
        float t[4] = {v.x + u.x, v.y + u.y, v.z + u.z, v.w + u.w};
        #pragma unroll
        for (int c = 0; c < 4; ++c) {
            const float* p = pk + c * 16;
            float xn = fmaf((t[c] - mu) * rstd, p[0], p[1]);
            float r = fmaxf(xn, 0.f);
            #pragma unroll
            for (int h = 0; h < HH; ++h)
                part[h] = fmaf(r, p[2 + h], part[h]);
        }
    }
    int i = wi + 1;
    float nav = na[((size_t)b * NSS + i) * NSS + (lane + 1)];
    #pragma unroll
    for (int h = 0; h < HH; ++h)
        se[(((size_t)b * HH + h) * NSS + i) * NSS + (lane + 1)] =
            nav * (part[h] + cvec[16 + h]);
    if (lane == 0) {
        #pragma unroll
        for (int h = 0; h < HH; ++h)
            se[(((size_t)b * HH + h) * NSS + i) * NSS] = 0.f;
    }
}

// se border row i=0 (old reduction style; only B*NS blocks)
__global__ void se_border(const float* __restrict__ U, const float* __restrict__ V,
                          const float* __restrict__ be1, const float* __restrict__ PK,
                          const float* __restrict__ cvec, float* __restrict__ se) {
    int b = blockIdx.x / NSS, j = blockIdx.x % NSS;
    int lane = threadIdx.x;
    float x[4];
    float ssum = 0.f;
    #pragma unroll
    for (int p = 0; p < 4; ++p) {
        int d = lane + 64 * p;
        float hv;
        if (j > 0) hv = U[((size_t)b * SS + j - 1) * DD + d] + V[((size_t)b * SS + j - 1) * DD + d];
        else hv = be1[d];
        x[p] = hv;
        ssum += hv;
    }
    #pragma unroll
    for (int off = 32; off; off >>= 1) ssum += __shfl_xor(ssum, off);
    float mu = ssum * (1.f / DD);
    float vs = 0.f;
    #pragma unroll
    for (int p = 0; p < 4; ++p) { float t = x[p] - mu; vs = fmaf(t, t, vs); }
    #pragma unroll
    for (int off = 32; off; off >>= 1) vs += __shfl_xor(vs, off);
    float rstd = rsqrtf(vs * (1.f / DD) + LN_EPS);
    float part[HH];
    #pragma unroll
    for (int h = 0; h < HH; ++h) part[h] = 0.f;
    #pragma unroll
    for (int p = 0; p < 4; ++p) {
        int d = lane + 64 * p;
        float xn = fmaf((x[p] - mu) * rstd, PK[d * 16], PK[d * 16 + 1]);
        float r = fmaxf(xn, 0.f);
        #pragma unroll
        for (int h = 0; h < HH; ++h)
            part[h] = fmaf(r, PK[d * 16 + 2 + h], part[h]);
    }
    #pragma unroll
    for (int h = 0; h < HH; ++h) {
        #pragma unroll
        for (int off = 32; off; off >>= 1) part[h] += __shfl_xor(part[h], off);
    }
    if (lane == 0) {
        #pragma unroll
        for (int h = 0; h < HH; ++h)
            se[(((size_t)b * HH + h) * NSS) * NSS + j] =
                (j > 0) ? (part[h] + cvec[16 + h]) : 0.f;
    }
}

// per (b,h,i): scores -> softmax -> aw + ctx ; 4 waves/block
__global__ __launch_bounds__(256) void attn_kernel4(
    const float* __restrict__ sq, const float* __restrict__ sk,
    const float* __restrict__ se, const float* __restrict__ na,
    const float* __restrict__ ba, const float* __restrict__ vbuf,
    float* __restrict__ aw_out, float* __restrict__ ctx) {
    int wid = threadIdx.x >> 6, lane = threadIdx.x & 63;
    int idx = blockIdx.x * 4 + wid;
    int bh = idx / NSS, i = idx % NSS;
    int b = bh / HH, h = bh % HH;
    __shared__ float awL[4][72];
    float sqv = sq[(size_t)bh * NSS + i];
    float bav = ba[0];
    float s0;
    {
        int j = lane;
        float sc = sqv + sk[(size_t)bh * NSS + j] + se[((size_t)bh * NSS + i) * NSS + j] + bav;
        if (na[(size_t)(b * NSS + i) * NSS + j] == 0.f) sc += -1e9f;
        s0 = sc;
    }
    float s1 = -3.4e38f;
    if (lane == 0) {
        int j = 64;
        float sc = sqv + sk[(size_t)bh * NSS + j] + se[((size_t)bh * NSS + i) * NSS + j] + bav;
        if (na[(size_t)(b * NSS + i) * NSS + j] == 0.f) sc += -1e9f;
        s1 = sc;
    }
    float m = fmaxf(s0, s1);
    #pragma unroll
    for (int off = 32; off; off >>= 1) m = fmaxf(m, __shfl_xor(m, off));
    float e0 = __expf(s0 - m);
    float e1 = (lane == 0) ? __expf(s1 - m) : 0.f;
    float tot = e0 + e1;
    #pragma unroll
    for (int off = 32; off; off >>= 1) tot += __shfl_xor(tot, off);
    float inv = 1.f / tot;
    float a0 = e0 * inv;
    float* awrow = aw_out + ((size_t)bh * NSS + i) * NSS;
    awL[wid][lane] = a0;
    awrow[lane] = a0;
    if (lane == 0) { awL[wid][64] = e1 * inv; awrow[64] = e1 * inv; }
    __syncthreads();
    if (lane < HDIM) {
        int d = lane;
        float acc = 0.f;
        #pragma unroll 5
        for (int j = 0; j < NSS; ++j)
            acc = fmaf(awL[wid][j], vbuf[(size_t)(b * NSS + j) * DD + h * HDIM + d], acc);
        ctx[(size_t)(b * NSS + i) * DD + h * HDIM + d] = acc;
    }
}

extern "C" void kernel_launch(void* const* d_in, const int* in_sizes, int n_in,
                              void* d_out, int out_size, void* d_ws, size_t ws_size,
                              hipStream_t stream) {
    const float* desc_emb = (const float*)d_in[0];
    const float* nve      = (const float*)d_in[1];
    const float* Wg  = (const float*)d_in[2];
    const float* bg  = (const float*)d_in[3];
    const float* Wq  = (const float*)d_in[4];
    const float* bq  = (const float*)d_in[5];
    const float* Wk  = (const float*)d_in[6];
    const float* bk  = (const float*)d_in[7];
    const float* Wv  = (const float*)d_in[8];
    const float* bv  = (const float*)d_in[9];
    const float* We1 = (const float*)d_in[10];
    const float* be1 = (const float*)d_in[11];
    const float* lng = (const float*)d_in[12];
    const float* lnb = (const float*)d_in[13];
    const float* We2 = (const float*)d_in[14];
    const float* be2 = (const float*)d_in[15];
    const float* Wa  = (const float*)d_in[16];
    const float* ba  = (const float*)d_in[17];
    const float* Wo  = (const float*)d_in[18];
    const float* bo  = (const float*)d_in[19];
    const float* tb  = (const float*)d_in[20];

    float* ws   = (float*)d_ws;
    float* desc = ws + OFF_DESC;
    float* U    = ws + OFF_U;
    float* V    = ws + OFF_V;
    float* vbuf = ws + OFF_VBUF;
    float* na   = ws + OFF_NA;
    float* se   = ws + OFF_SE;
    float* sq   = ws + OFF_SQ;
    float* sk   = ws + OFF_SK;
    float* ctx  = ws + OFF_CTX;
    float* PK   = ws + OFF_CTX;    // overlay: read only before attn writes ctx
    float* WgT   = ws + OFF_WGT;
    float* We1aT = ws + OFF_WE1AT;
    float* We1bT = ws + OFF_WE1BT;
    float* WvT   = ws + OFF_WVT;
    float* WoT   = ws + OFF_WOT;
    float* wqf  = ws + OFF_WQF;
    float* wkf  = ws + OFF_WKF;
    float* Mf   = ws + OFF_MF;
    float* cvec = ws + OFF_CVEC;
    float* rnd  = ws + OFF_RND;
    float* rnv  = ws + OFF_RNV;

    float* out = (float*)d_out;                  // [B][NS][D]
    float* aw  = out + (size_t)BB * NSS * DD;    // [B][H][NS][NS]

    transT<<<16, 256, 0, stream>>>(Wg, WgT, DD, 0);
    transT<<<16, 256, 0, stream>>>(We1, We1aT, 2 * DD, 0);
    transT<<<16, 256, 0, stream>>>(We1, We1bT, 2 * DD, DD);
    transT<<<16, 256, 0, stream>>>(Wv, WvT, DD, 0);
    transT<<<16, 256, 0, stream>>>(Wo, WoT, DD, 0);
    fold_attn<<<HH, DD, 0, stream>>>(Wq, bq, Wk, bk, We2, be2, Wa, wqf, wkf, Mf, cvec);
    build_pk<<<1, DD, 0, stream>>>(lng, lnb, Mf, PK);

    gemmR<<<BB * SS / GR, 256, 0, stream>>>(desc_emb, WgT, bg, desc, 1);
    rownorms<<<2 * BB * SS, 64, 0, stream>>>(desc, nve, rnd, rnv);
    gemmR<<<BB * SS / GR, 256, 0, stream>>>(desc, We1aT, be1, U, 1);   // fold be1
    gemmR<<<BB * SS / GR, 256, 0, stream>>>(desc, We1bT, be1, V, 0);
    gemmR<<<BB * NSS / GR, 256, 0, stream>>>(nve, WvT, bv, vbuf, 1);

    adj2_kernel<<<BB * 16, 256, 0, stream>>>(desc, nve, rnd, rnv, tb, na);
    sqsk_kernel<<<BB * NSS, 64, 0, stream>>>(nve, wqf, wkf, cvec, sq, sk);
    se_border<<<BB * NSS, 64, 0, stream>>>(U, V, be1, PK, cvec, se);
    se2_kernel<<<BB * 16, 256, 0, stream>>>(U, V, PK, cvec, na, se);
    attn_kernel4<<<BB * HH * NSS / 4, 256, 0, stream>>>(sq, sk, se, na, ba, vbuf, aw, ctx);
    gemmR<<<BB * NSS / GR, 256, 0, stream>>>(ctx, WoT, bo, out, 1);
}